// Round 2
// baseline (947.091 us; speedup 1.0000x reference)
//
#include <hip/hip_runtime.h>
#include <math.h>

#define B_ 8192
#define M_ 200

// Pre-transposed weights (written by prep_kernel every call, then read by policy_kernel)
__device__ float g_w1t[51200];   // [32][5][5][64], scaled by 1/max_vec[l]
__device__ float g_w2t[36864];   // [64][3][3][64]
__device__ float g_fc1t[32768];  // [256][128]
__device__ float g_enct[16384];  // [128][128]
__device__ float g_crt[131072];  // [128][1024]
__device__ float g_act[65536];   // [128][512]

__global__ __launch_bounds__(256) void prep_kernel(
    const float* __restrict__ w1, const float* __restrict__ w2,
    const float* __restrict__ fc1, const float* __restrict__ enc,
    const float* __restrict__ cr, const float* __restrict__ ac,
    const float* __restrict__ maxv)
{
    int d = blockIdx.x * 256 + threadIdx.x;
    if (d < 51200) {
        int oc = d & 63, r = d >> 6;
        int l = r / 25, q = r % 25;
        g_w1t[d] = w1[oc * 800 + l * 25 + q] / maxv[l];
        return;
    }
    d -= 51200;
    if (d < 36864) {
        int oc = d & 63, r = d >> 6;
        int ic = r / 9, q = r % 9;
        g_w2t[d] = w2[oc * 576 + ic * 9 + q];
        return;
    }
    d -= 36864;
    if (d < 32768) { int o = d & 127, i = d >> 7;  g_fc1t[d] = fc1[o * 256 + i]; return; }
    d -= 32768;
    if (d < 16384) { int o = d & 127, i = d >> 7;  g_enct[d] = enc[o * 128 + i]; return; }
    d -= 16384;
    if (d < 131072){ int o = d & 1023, i = d >> 10; g_crt[d] = cr[o * 128 + i]; return; }
    d -= 131072;
    if (d < 65536) { int o = d & 511, i = d >> 9;  g_act[d] = ac[o * 128 + i]; return; }
}

__global__ __launch_bounds__(256) void policy_kernel(
    const int*   __restrict__ obs,
    const float* __restrict__ b1,  const float* __restrict__ b2,
    const float* __restrict__ fc1b,const float* __restrict__ encb,
    const float* __restrict__ crb, const float* __restrict__ vw,
    const float* __restrict__ vb,  const float* __restrict__ acb,
    const float* __restrict__ emb, const float* __restrict__ aW,
    const float* __restrict__ abias,
    float* __restrict__ out)
{
    const int b   = blockIdx.x;
    const int tid = threadIdx.x;

    __shared__ int   s_obs[600];
    __shared__ int   s_cell[200];
    __shared__ float s_cval[200];
    __shared__ float s_part[4][64][16];   // 16 KB conv1 partials
    __shared__ float s_act1[64 * 16];     // conv1 output (relu)
    __shared__ float s_c2[256];           // conv2 output flat [oc*4 + px*2 + py]
    __shared__ float s_fp[256];
    __shared__ float s_fc1[128];
    __shared__ float s_hid[128];
    __shared__ float s_af[512];
    __shared__ float s_qp[256];
    __shared__ float s_q[16];
    __shared__ float s_vred[4];

    // ---- phase 0: load tokens, compute cells
    for (int k = tid; k < 600; k += 256) s_obs[k] = obs[b * 600 + k];
    __syncthreads();
    if (tid < 200) {
        int coord = s_obs[tid * 3], atr = s_obs[tid * 3 + 1];
        int valid = (coord != 255) && (atr < 32);
        int x = (coord >> 4) & 15, y = coord & 15;
        s_cell[tid] = valid ? (atr * 256 + x * 16 + y) : 0;  // invalid -> cell 0 (matches ref)
    }
    __syncthreads();

    // ---- phase 1: last-wins duplicate resolution (numpy scatter-set semantics)
    if (tid < 200) {
        int c = s_cell[tid];
        bool kept = true;
        for (int j = tid + 1; j < 200; j++)
            if (s_cell[j] == c) { kept = false; break; }
        int coord = s_obs[tid * 3], atr = s_obs[tid * 3 + 1], val = s_obs[tid * 3 + 2];
        int valid = (coord != 255) && (atr < 32);
        int x = (coord >> 4) & 15, y = coord & 15;
        // x>=14 or y>=14 cells are never read by the 5x5/s3 VALID conv
        s_cval[tid] = (kept && valid && x < 14 && y < 14) ? (float)val : 0.f;
    }
    {   // zero conv1 partials
        float* pp = &s_part[0][0][0];
        for (int k = tid; k < 4096; k += 256) pp[k] = 0.f;
    }
    __syncthreads();

    // ---- phase 2: sparse conv1 (scatter tokens into [64][4][4] output)
    {
        const int oc = tid & 63, g = tid >> 6;   // wave-uniform g, lane=oc
        for (int k = g; k < 200; k += 4) {
            float v = s_cval[k];
            if (v != 0.f) {                       // wave-uniform predicate
                int c = s_cell[k];
                int l = c >> 8, x = (c >> 4) & 15, y = c & 15;
                int x3 = x / 3, rx = x - 3 * x3;
                int y3 = y / 3, ry = y - 3 * y3;
                const float* wl = &g_w1t[l * 1600 + oc];
                bool ax = (x3 <= 3), bx = (x3 >= 1) && (rx <= 1);
                bool ay = (y3 <= 3), by = (y3 >= 1) && (ry <= 1);
                if (ax && ay) atomicAdd(&s_part[g][oc][x3 * 4 + y3],           v * wl[(rx * 5 + ry) * 64]);
                if (ax && by) atomicAdd(&s_part[g][oc][x3 * 4 + (y3 - 1)],     v * wl[(rx * 5 + ry + 3) * 64]);
                if (bx && ay) atomicAdd(&s_part[g][oc][(x3 - 1) * 4 + y3],     v * wl[((rx + 3) * 5 + ry) * 64]);
                if (bx && by) atomicAdd(&s_part[g][oc][(x3 - 1) * 4 + (y3 - 1)], v * wl[((rx + 3) * 5 + ry + 3) * 64]);
            }
        }
    }
    __syncthreads();

    // ---- phase 3: reduce partials + bias + relu
    for (int r = 0; r < 4; r++) {
        int o = tid + 256 * r;            // o = oc*16 + pos
        int oc = o >> 4, pos = o & 15;
        float s = s_part[0][oc][pos] + s_part[1][oc][pos]
                + s_part[2][oc][pos] + s_part[3][oc][pos] + b1[oc];
        s_act1[o] = fmaxf(s, 0.f);
    }
    __syncthreads();

    // ---- phase 4: conv2 3x3 (4x4 -> 2x2)
    {
        const int oc = tid & 63, pos = tid >> 6;
        const int px = pos >> 1, py = pos & 1;
        float acc = b2[oc];
        const float* wp = &g_w2t[oc];
        const float* ap = &s_act1[px * 4 + py];
        for (int ic = 0; ic < 64; ic++) {
            #pragma unroll
            for (int kx = 0; kx < 3; kx++)
                #pragma unroll
                for (int ky = 0; ky < 3; ky++)
                    acc += ap[ic * 16 + kx * 4 + ky] * wp[(ic * 9 + kx * 3 + ky) * 64];
        }
        s_c2[oc * 4 + pos] = fmaxf(acc, 0.f);   // matches reshape order oc*4+px*2+py
    }
    __syncthreads();

    // ---- phase 5: fc1 (256 -> 128), split K across 2 halves
    {
        int o = tid & 127, h = tid >> 7;
        float acc = 0.f;
        for (int k = 0; k < 128; k++)
            acc += s_c2[h * 128 + k] * g_fc1t[(h * 128 + k) * 128 + o];
        s_fp[tid] = acc;
    }
    __syncthreads();
    if (tid < 128) s_fc1[tid] = fmaxf(s_fp[tid] + s_fp[tid + 128] + fc1b[tid], 0.f);
    __syncthreads();

    // ---- phase 6: encoder (128 -> 128)
    {
        int o = tid & 127, h = tid >> 7;
        float acc = 0.f;
        for (int k = 0; k < 64; k++)
            acc += s_fc1[h * 64 + k] * g_enct[(h * 64 + k) * 128 + o];
        s_fp[tid] = acc;
    }
    __syncthreads();
    if (tid < 128) s_hid[tid] = fmaxf(s_fp[tid] + s_fp[tid + 128] + encb[tid], 0.f);
    __syncthreads();

    // ---- phase 7: critic (128 -> 1024 tanh) fused with value dot
    {
        float vpart = 0.f;
        for (int r = 0; r < 4; r++) {
            int o = tid + 256 * r;
            float acc = crb[o];
            for (int i = 0; i < 128; i++)
                acc += s_hid[i] * g_crt[i * 1024 + o];
            vpart += tanhf(acc) * vw[o];
        }
        #pragma unroll
        for (int off = 32; off > 0; off >>= 1)
            vpart += __shfl_down(vpart, off);
        if ((tid & 63) == 0) s_vred[tid >> 6] = vpart;
    }
    __syncthreads();
    if (tid == 0)
        out[B_ * 100 + b] = s_vred[0] + s_vred[1] + s_vred[2] + s_vred[3] + vb[0];

    // ---- phase 8: actor1 (128 -> 512 relu)
    for (int r = 0; r < 2; r++) {
        int o = tid + 256 * r;
        float acc = acb[o];
        for (int i = 0; i < 128; i++)
            acc += s_hid[i] * g_act[i * 512 + o];
        s_af[o] = fmaxf(acc, 0.f);
    }
    __syncthreads();

    // ---- phase 9: query = tanh(af @ actor_W)  (512 -> 16)
    {
        int e = tid & 15, ch = tid >> 4;
        float acc = 0.f;
        for (int j = 0; j < 32; j++) {
            int jj = ch * 32 + j;
            acc += s_af[jj] * aW[jj * 16 + e];
        }
        s_qp[ch * 16 + e] = acc;
    }
    __syncthreads();
    if (tid < 16) {
        float acc = 0.f;
        for (int ch = 0; ch < 16; ch++) acc += s_qp[ch * 16 + tid];
        s_q[tid] = tanhf(acc);
    }
    __syncthreads();

    // ---- phase 10: logits (16 -> 100)
    if (tid < 100) {
        float acc = abias[0];
        #pragma unroll
        for (int e = 0; e < 16; e++) acc += s_q[e] * emb[tid * 16 + e];
        out[b * 100 + tid] = acc;
    }
}

extern "C" void kernel_launch(void* const* d_in, const int* in_sizes, int n_in,
                              void* d_out, int out_size, void* d_ws, size_t ws_size,
                              hipStream_t stream) {
    const int*   obs   = (const int*)  d_in[0];
    const float* maxv  = (const float*)d_in[1];
    const float* w1    = (const float*)d_in[2];
    const float* b1    = (const float*)d_in[3];
    const float* w2    = (const float*)d_in[4];
    const float* b2    = (const float*)d_in[5];
    const float* fc1w  = (const float*)d_in[6];
    const float* fc1b  = (const float*)d_in[7];
    const float* encw  = (const float*)d_in[8];
    const float* encb  = (const float*)d_in[9];
    const float* crw   = (const float*)d_in[10];
    const float* crb   = (const float*)d_in[11];
    const float* vw    = (const float*)d_in[12];
    const float* vb    = (const float*)d_in[13];
    const float* acw   = (const float*)d_in[14];
    const float* acb   = (const float*)d_in[15];
    const float* emb   = (const float*)d_in[16];
    const float* aW    = (const float*)d_in[17];
    const float* abias = (const float*)d_in[18];
    float* out = (float*)d_out;

    prep_kernel<<<1304, 256, 0, stream>>>(w1, w2, fc1w, encw, crw, acw, maxv);
    policy_kernel<<<B_, 256, 0, stream>>>(obs, b1, b2, fc1b, encb, crb, vw, vb,
                                          acb, emb, aW, abias, out);
}

// Round 3
// 861.406 us; speedup vs baseline: 1.0995x; 1.0995x over previous
//
#include <hip/hip_runtime.h>
#include <math.h>

#define B_ 8192

typedef __attribute__((ext_vector_type(8))) short short8;
typedef __attribute__((ext_vector_type(4))) float f32x4;

// ---------------- persistent device buffers (rewritten every call) ----------------
// weights (hi/lo split bf16, stored as B^T row-major [N][K])
__device__ float          g_w1t[51200];                    // conv1 [32][5][5][64] fp32, /max_vec
__device__ unsigned short g_w2hi[36864],  g_w2lo[36864];   // conv2 [64][576]
__device__ unsigned short g_fc1hi[32768], g_fc1lo[32768];  // fc1   [128][256] (k'=pos*64+oc)
__device__ unsigned short g_enchi[16384], g_enclo[16384];  // enc   [128][128]
__device__ unsigned short g_crhi[131072], g_crlo[131072];  // critic[1024][128]
__device__ unsigned short g_achi[65536],  g_aclo[65536];   // actor [512][128]
__device__ unsigned short g_qWhi[8192],   g_qWlo[8192];    // actor_W^T [16][512]
// activations (hi/lo split bf16, row-major [M][K])
__device__ unsigned short g_A0hi[32768*576], g_A0lo[32768*576]; // im2col of conv1 out
__device__ unsigned short g_A1hi[8192*256],  g_A1lo[8192*256];  // conv2 out (=[s][pos*64+oc])
__device__ unsigned short g_A2hi[8192*128],  g_A2lo[8192*128];  // fc1 out
__device__ unsigned short g_Hhi[8192*128],   g_Hlo[8192*128];   // enc out (hidden)
__device__ unsigned short g_AFhi[8192*512],  g_AFlo[8192*512];  // actor out

__device__ __forceinline__ unsigned short f2bf(float v){
    unsigned u = __builtin_bit_cast(unsigned, v);
    unsigned r = (u + 0x7fffu + ((u >> 16) & 1u)) >> 16;   // RN-even (finite inputs)
    return (unsigned short)r;
}
__device__ __forceinline__ float bf2f(unsigned short h){
    unsigned u = ((unsigned)h) << 16;
    return __builtin_bit_cast(float, u);
}
__device__ __forceinline__ void split_store(float v, unsigned short* hi, unsigned short* lo){
    unsigned short h = f2bf(v);
    *hi = h;
    *lo = f2bf(v - bf2f(h));
}

// ---------------- prep: transpose + split all weights ----------------
__global__ __launch_bounds__(256) void prep_kernel(
    const float* __restrict__ w1, const float* __restrict__ maxv,
    const float* __restrict__ w2, const float* __restrict__ fc1,
    const float* __restrict__ enc, const float* __restrict__ cr,
    const float* __restrict__ ac, const float* __restrict__ aW)
{
    int d = blockIdx.x * 256 + threadIdx.x;
    if (d < 51200){
        int oc = d & 63, r = d >> 6;
        int l = r / 25, q = r - l*25;
        g_w1t[d] = w1[oc*800 + l*25 + q] / maxv[l];
        return;
    }
    d -= 51200;
    if (d < 36864){ split_store(w2[d], &g_w2hi[d], &g_w2lo[d]); return; }
    d -= 36864;
    if (d < 32768){
        int o = d >> 8, kp = d & 255;                      // k' = pos*64+oc
        split_store(fc1[o*256 + (kp & 63)*4 + (kp >> 6)], &g_fc1hi[d], &g_fc1lo[d]);
        return;
    }
    d -= 32768;
    if (d < 16384){ split_store(enc[d], &g_enchi[d], &g_enclo[d]); return; }
    d -= 16384;
    if (d < 131072){ split_store(cr[d], &g_crhi[d], &g_crlo[d]); return; }
    d -= 131072;
    if (d < 65536){ split_store(ac[d], &g_achi[d], &g_aclo[d]); return; }
    d -= 65536;
    { int e = d >> 9, j = d & 511; split_store(aW[j*16 + e], &g_qWhi[d], &g_qWlo[d]); }
}

// ---------------- front-end: scatter + sparse conv1 + im2col split-write ----------------
__global__ __launch_bounds__(256) void frontend_kernel(const int* __restrict__ obs,
                                                       const float* __restrict__ b1)
{
    const int b = blockIdx.x, tid = threadIdx.x;
    __shared__ int   s_obs[600];
    __shared__ int   s_cell[200];
    __shared__ float s_cval[200];
    __shared__ char  s_u[32768];                 // winner[8192] int, then part[4][64][16]
    int*   winner = (int*)s_u;
    float* part   = (float*)s_u;
    float* act1   = (float*)(s_u + 16384);       // [64][16]

    for (int k = tid; k < 600; k += 256) s_obs[k] = obs[b*600 + k];
    for (int k = tid; k < 8192; k += 256) winner[k] = -1;
    __syncthreads();
    if (tid < 200){
        int coord = s_obs[tid*3], atr = s_obs[tid*3+1];
        bool valid = (coord != 255) && (atr < 32);
        int x = (coord >> 4) & 15, y = coord & 15;
        int cell = valid ? (atr*256 + x*16 + y) : 0;   // invalid claims cell 0 (ref semantics)
        s_cell[tid] = cell;
        atomicMax(&winner[cell], tid);                  // last index wins
    }
    __syncthreads();
    if (tid < 200){
        int cell = s_cell[tid];
        bool kept = (winner[cell] == tid);
        int coord = s_obs[tid*3], atr = s_obs[tid*3+1], val = s_obs[tid*3+2];
        bool valid = (coord != 255) && (atr < 32);
        int x = (coord >> 4) & 15, y = coord & 15;
        // x>=14 / y>=14 never read by 5x5/s3 VALID conv
        s_cval[tid] = (kept && valid && x < 14 && y < 14) ? (float)val : 0.f;
    }
    __syncthreads();
    for (int k = tid; k < 4096; k += 256) part[k] = 0.f;
    __syncthreads();
    // sparse conv1: scatter tokens into [64][4][4]
    {
        const int oc = tid & 63, g = tid >> 6;
        for (int k = g; k < 200; k += 4){
            float v = s_cval[k];
            if (v != 0.f){
                int c = s_cell[k];
                int l = c >> 8, x = (c >> 4) & 15, y = c & 15;
                int x3 = x/3, rx = x - 3*x3;
                int y3 = y/3, ry = y - 3*y3;
                const float* wl = &g_w1t[l*1600 + oc];
                float* pg = &part[g*1024 + oc*16];
                bool ax = (x3 <= 3), bx = (x3 >= 1) && (rx <= 1);
                bool ay = (y3 <= 3), by = (y3 >= 1) && (ry <= 1);
                if (ax && ay) atomicAdd(&pg[x3*4 + y3],       v*wl[(rx*5+ry)*64]);
                if (ax && by) atomicAdd(&pg[x3*4 + y3-1],     v*wl[(rx*5+ry+3)*64]);
                if (bx && ay) atomicAdd(&pg[(x3-1)*4 + y3],   v*wl[((rx+3)*5+ry)*64]);
                if (bx && by) atomicAdd(&pg[(x3-1)*4 + y3-1], v*wl[((rx+3)*5+ry+3)*64]);
            }
        }
    }
    __syncthreads();
    for (int r = 0; r < 4; r++){
        int o = tid + 256*r;                     // o = oc*16 + pos
        int oc = o >> 4;
        float s = part[o] + part[1024+o] + part[2048+o] + part[3072+o] + b1[oc];
        act1[o] = fmaxf(s, 0.f);
    }
    __syncthreads();
    // im2col (4 rows of 576) split to bf16 hi/lo, contiguous coalesced
    for (int f = tid; f < 2304; f += 256){
        int pos = f / 576, k = f - pos*576;
        int ic = k / 9, r = k - ic*9;
        int kx = r / 3, ky = r - kx*3;
        int px = pos >> 1, py = pos & 1;
        float v = act1[ic*16 + (px+kx)*4 + (py+ky)];
        unsigned short h = f2bf(v);
        g_A0hi[b*2304 + f] = h;
        g_A0lo[b*2304 + f] = f2bf(v - bf2f(h));
    }
}

// ---------------- generic 64x64 split-bf16 MFMA GEMM with relu+bias, split C-store ----------
// LAYER: 0=conv2(K576,N64) 1=fc1(K256,N128) 2=enc(K128,N128) 3=actor(K128,N512)
template<int LAYER>
__global__ __launch_bounds__(256) void gemm64_kernel(const float* __restrict__ bias)
{
    constexpr int K = (LAYER==0) ? 576 : (LAYER==1) ? 256 : 128;
    constexpr int N = (LAYER==0) ? 64  : (LAYER==3) ? 512 : 128;
    const unsigned short *Ahi, *Alo, *Bh, *Bl;
    unsigned short *Chi, *Clo;
    if constexpr (LAYER==0){ Ahi=g_A0hi; Alo=g_A0lo; Bh=g_w2hi;  Bl=g_w2lo;  Chi=g_A1hi; Clo=g_A1lo; }
    else if constexpr (LAYER==1){ Ahi=g_A1hi; Alo=g_A1lo; Bh=g_fc1hi; Bl=g_fc1lo; Chi=g_A2hi; Clo=g_A2lo; }
    else if constexpr (LAYER==2){ Ahi=g_A2hi; Alo=g_A2lo; Bh=g_enchi; Bl=g_enclo; Chi=g_Hhi;  Clo=g_Hlo; }
    else                        { Ahi=g_Hhi;  Alo=g_Hlo;  Bh=g_achi;  Bl=g_aclo;  Chi=g_AFhi; Clo=g_AFlo; }

    const int r0 = blockIdx.x * 64, c0 = blockIdx.y * 64;
    const int tid = threadIdx.x, wave = tid >> 6, lane = tid & 63;
    const int l15 = lane & 15, lhi = lane >> 4;

    __shared__ unsigned short sAhi[64][72];      // +8 bf16 pad -> conflict-free b128 reads
    __shared__ unsigned short sAlo[64][72];

    f32x4 acc[4] = {{0,0,0,0},{0,0,0,0},{0,0,0,0},{0,0,0,0}};
    for (int kb = 0; kb < K; kb += 64){
        __syncthreads();
        #pragma unroll
        for (int u = 0; u < 2; u++){
            int unit = tid + u*256;
            int row = unit >> 3, ch = (unit & 7) * 8;
            int g = (r0 + row)*K + kb + ch;
            *(short8*)&sAhi[row][ch] = *(const short8*)&Ahi[g];
            *(short8*)&sAlo[row][ch] = *(const short8*)&Alo[g];
        }
        __syncthreads();
        #pragma unroll
        for (int ks = 0; ks < 2; ks++){
            const int kk = ks*32 + lhi*8;
            short8 ah = *(const short8*)&sAhi[wave*16 + l15][kk];
            short8 al = *(const short8*)&sAlo[wave*16 + l15][kk];
            #pragma unroll
            for (int nt = 0; nt < 4; nt++){
                const int n = c0 + nt*16 + l15;
                const short8 bh = *(const short8*)&Bh[n*K + kb + kk];
                const short8 bl = *(const short8*)&Bl[n*K + kb + kk];
                acc[nt] = __builtin_amdgcn_mfma_f32_16x16x32_bf16(ah, bh, acc[nt], 0, 0, 0);
                acc[nt] = __builtin_amdgcn_mfma_f32_16x16x32_bf16(al, bh, acc[nt], 0, 0, 0);
                acc[nt] = __builtin_amdgcn_mfma_f32_16x16x32_bf16(ah, bl, acc[nt], 0, 0, 0);
            }
        }
    }
    #pragma unroll
    for (int nt = 0; nt < 4; nt++){
        const int col = c0 + nt*16 + l15;
        const float bb = bias[col];
        #pragma unroll
        for (int j = 0; j < 4; j++){
            const int row = r0 + wave*16 + lhi*4 + j;
            float v = fmaxf(acc[nt][j] + bb, 0.f);
            unsigned short h = f2bf(v);
            Chi[row*N + col] = h;
            Clo[row*N + col] = f2bf(v - bf2f(h));
        }
    }
}

// ---------------- critic: [16 rows] x 1024 cols, tanh + vw dot -> value ----------------
__global__ __launch_bounds__(256) void critic_kernel(const float* __restrict__ crb,
    const float* __restrict__ vw, const float* __restrict__ vb, float* __restrict__ outv)
{
    const int r0 = blockIdx.x * 16;
    const int tid = threadIdx.x, wave = tid >> 6, lane = tid & 63;
    const int l15 = lane & 15, lhi = lane >> 4;
    __shared__ unsigned short sAhi[16][136], sAlo[16][136];
    __shared__ float s_v[4][16];
    {
        int row = tid >> 4, ch = (tid & 15) * 8;
        int g = (r0 + row)*128 + ch;
        *(short8*)&sAhi[row][ch] = *(const short8*)&g_Hhi[g];
        *(short8*)&sAlo[row][ch] = *(const short8*)&g_Hlo[g];
    }
    __syncthreads();
    f32x4 acc[16];
    #pragma unroll
    for (int nt = 0; nt < 16; nt++) acc[nt] = f32x4{0,0,0,0};
    #pragma unroll
    for (int ks = 0; ks < 4; ks++){
        const int kk = ks*32 + lhi*8;
        short8 ah = *(const short8*)&sAhi[l15][kk];
        short8 al = *(const short8*)&sAlo[l15][kk];
        #pragma unroll
        for (int nt = 0; nt < 16; nt++){
            const int n = wave*256 + nt*16 + l15;
            const short8 bh = *(const short8*)&g_crhi[n*128 + kk];
            const short8 bl = *(const short8*)&g_crlo[n*128 + kk];
            acc[nt] = __builtin_amdgcn_mfma_f32_16x16x32_bf16(ah, bh, acc[nt], 0, 0, 0);
            acc[nt] = __builtin_amdgcn_mfma_f32_16x16x32_bf16(al, bh, acc[nt], 0, 0, 0);
            acc[nt] = __builtin_amdgcn_mfma_f32_16x16x32_bf16(ah, bl, acc[nt], 0, 0, 0);
        }
    }
    float vp[4] = {0.f, 0.f, 0.f, 0.f};
    #pragma unroll
    for (int nt = 0; nt < 16; nt++){
        const int col = wave*256 + nt*16 + l15;
        const float w = vw[col], bb = crb[col];
        #pragma unroll
        for (int j = 0; j < 4; j++) vp[j] += tanhf(acc[nt][j] + bb) * w;
    }
    #pragma unroll
    for (int m = 1; m < 16; m <<= 1){
        #pragma unroll
        for (int j = 0; j < 4; j++) vp[j] += __shfl_xor(vp[j], m, 64);
    }
    if (l15 == 0){
        #pragma unroll
        for (int j = 0; j < 4; j++) s_v[wave][lhi*4 + j] = vp[j];
    }
    __syncthreads();
    if (tid < 16)
        outv[r0 + tid] = s_v[0][tid] + s_v[1][tid] + s_v[2][tid] + s_v[3][tid] + vb[0];
}

// ---------------- query (AF @ actor_W^T, tanh) fused with logits ----------------
__global__ __launch_bounds__(256) void query_kernel(const float* __restrict__ emb,
    const float* __restrict__ abias, float* __restrict__ out)
{
    const int r0 = blockIdx.x * 64;
    const int tid = threadIdx.x, wave = tid >> 6, lane = tid & 63;
    const int l15 = lane & 15, lhi = lane >> 4;
    __shared__ unsigned short sAhi[64][72], sAlo[64][72];
    __shared__ float s_q[64][16];
    __shared__ float s_emb[1600];
    for (int k = tid; k < 1600; k += 256) s_emb[k] = emb[k];
    f32x4 acc = {0,0,0,0};
    for (int kb = 0; kb < 512; kb += 64){
        __syncthreads();
        #pragma unroll
        for (int u = 0; u < 2; u++){
            int unit = tid + u*256;
            int row = unit >> 3, ch = (unit & 7) * 8;
            int g = (r0 + row)*512 + kb + ch;
            *(short8*)&sAhi[row][ch] = *(const short8*)&g_AFhi[g];
            *(short8*)&sAlo[row][ch] = *(const short8*)&g_AFlo[g];
        }
        __syncthreads();
        #pragma unroll
        for (int ks = 0; ks < 2; ks++){
            const int kk = ks*32 + lhi*8;
            short8 ah = *(const short8*)&sAhi[wave*16 + l15][kk];
            short8 al = *(const short8*)&sAlo[wave*16 + l15][kk];
            const short8 bh = *(const short8*)&g_qWhi[l15*512 + kb + kk];
            const short8 bl = *(const short8*)&g_qWlo[l15*512 + kb + kk];
            acc = __builtin_amdgcn_mfma_f32_16x16x32_bf16(ah, bh, acc, 0, 0, 0);
            acc = __builtin_amdgcn_mfma_f32_16x16x32_bf16(al, bh, acc, 0, 0, 0);
            acc = __builtin_amdgcn_mfma_f32_16x16x32_bf16(ah, bl, acc, 0, 0, 0);
        }
    }
    #pragma unroll
    for (int j = 0; j < 4; j++)
        s_q[wave*16 + lhi*4 + j][l15] = tanhf(acc[j]);
    __syncthreads();
    for (int i = tid; i < 6400; i += 256){
        int row = i / 100, a = i - row*100;
        float s = abias[0];
        #pragma unroll
        for (int e = 0; e < 16; e++) s += s_q[row][e] * s_emb[a*16 + e];
        out[(r0 + row)*100 + a] = s;
    }
}

// ---------------- launch ----------------
extern "C" void kernel_launch(void* const* d_in, const int* in_sizes, int n_in,
                              void* d_out, int out_size, void* d_ws, size_t ws_size,
                              hipStream_t stream) {
    const int*   obs   = (const int*)  d_in[0];
    const float* maxv  = (const float*)d_in[1];
    const float* w1    = (const float*)d_in[2];
    const float* b1    = (const float*)d_in[3];
    const float* w2    = (const float*)d_in[4];
    const float* b2    = (const float*)d_in[5];
    const float* fc1w  = (const float*)d_in[6];
    const float* fc1b  = (const float*)d_in[7];
    const float* encw  = (const float*)d_in[8];
    const float* encb  = (const float*)d_in[9];
    const float* crw   = (const float*)d_in[10];
    const float* crb   = (const float*)d_in[11];
    const float* vw    = (const float*)d_in[12];
    const float* vb    = (const float*)d_in[13];
    const float* acw   = (const float*)d_in[14];
    const float* acb   = (const float*)d_in[15];
    const float* emb   = (const float*)d_in[16];
    const float* aW    = (const float*)d_in[17];
    const float* abias = (const float*)d_in[18];
    float* out = (float*)d_out;

    prep_kernel<<<1336, 256, 0, stream>>>(w1, maxv, w2, fc1w, encw, crw, acw, aW);
    frontend_kernel<<<B_, 256, 0, stream>>>(obs, b1);
    gemm64_kernel<0><<<dim3(512, 1), 256, 0, stream>>>(b2);    // conv2
    gemm64_kernel<1><<<dim3(128, 2), 256, 0, stream>>>(fc1b);  // fc1
    gemm64_kernel<2><<<dim3(128, 2), 256, 0, stream>>>(encb);  // enc
    gemm64_kernel<3><<<dim3(128, 8), 256, 0, stream>>>(acb);   // actor
    critic_kernel<<<512, 256, 0, stream>>>(crb, vw, vb, out + B_*100);
    query_kernel<<<128, 256, 0, stream>>>(emb, abias, out);
}

// Round 6
// 844.079 us; speedup vs baseline: 1.1220x; 1.0205x over previous
//
#include <hip/hip_runtime.h>
#include <math.h>

#define B_ 8192

typedef __attribute__((ext_vector_type(8))) short short8;
typedef __attribute__((ext_vector_type(4))) float f32x4;

// ---------------- persistent device buffers (rewritten every call) ----------------
// weights (hi/lo split bf16, stored as B^T row-major [N][K])
__device__ float          g_w1t[51200];                    // conv1 [l*25+q][64] fp32, /max_vec
__device__ unsigned short g_w2hi[36864],  g_w2lo[36864];   // conv2 [64][576], k'=(kx*3+ky)*64+ic
__device__ unsigned short g_fc1hi[32768], g_fc1lo[32768];  // fc1   [128][256] (k'=pos*64+oc)
__device__ unsigned short g_enchi[16384], g_enclo[16384];  // enc   [128][128]
__device__ unsigned short g_crhi[131072], g_crlo[131072];  // critic[1024][128]
__device__ unsigned short g_achi[65536],  g_aclo[65536];   // actor [512][128]
__device__ unsigned short g_qWhi[8192],   g_qWlo[8192];    // actor_W^T [16][512]
// activations (hi/lo split bf16)
__device__ unsigned short g_ACT1hi[8192*1024], g_ACT1lo[8192*1024]; // conv1 out [s][cell16*64+oc]
__device__ unsigned short g_A1hi[8192*256],  g_A1lo[8192*256];  // conv2 out [s][pos*64+oc]
__device__ unsigned short g_A2hi[8192*128],  g_A2lo[8192*128];  // fc1 out
__device__ unsigned short g_Hhi[8192*128],   g_Hlo[8192*128];   // enc out (hidden)
__device__ unsigned short g_AFhi[8192*512],  g_AFlo[8192*512];  // actor out

__device__ __forceinline__ unsigned short f2bf(float v){
    unsigned u = __builtin_bit_cast(unsigned, v);
    unsigned r = (u + 0x7fffu + ((u >> 16) & 1u)) >> 16;   // RN-even (finite inputs)
    return (unsigned short)r;
}
__device__ __forceinline__ float bf2f(unsigned short h){
    unsigned u = ((unsigned)h) << 16;
    return __builtin_bit_cast(float, u);
}
__device__ __forceinline__ void split_store(float v, unsigned short* hi, unsigned short* lo){
    unsigned short h = f2bf(v);
    *hi = h;
    *lo = f2bf(v - bf2f(h));
}

// ---------------- prep: transpose + split all weights ----------------
__global__ __launch_bounds__(256) void prep_kernel(
    const float* __restrict__ w1, const float* __restrict__ maxv,
    const float* __restrict__ w2, const float* __restrict__ fc1,
    const float* __restrict__ enc, const float* __restrict__ cr,
    const float* __restrict__ ac, const float* __restrict__ aW)
{
    int d = blockIdx.x * 256 + threadIdx.x;
    if (d < 51200){
        int oc = d & 63, r = d >> 6;
        int l = r / 25, q = r - l*25;
        g_w1t[d] = w1[oc*800 + l*25 + q] / maxv[l];
        return;
    }
    d -= 51200;
    if (d < 36864){
        int oc = d / 576, k2 = d - oc*576;
        int kxy = k2 >> 6, ic = k2 & 63;               // k' = kxy*64 + ic
        split_store(w2[oc*576 + ic*9 + kxy], &g_w2hi[d], &g_w2lo[d]);
        return;
    }
    d -= 36864;
    if (d < 32768){
        int o = d >> 8, kp = d & 255;                  // k' = pos*64+oc
        split_store(fc1[o*256 + (kp & 63)*4 + (kp >> 6)], &g_fc1hi[d], &g_fc1lo[d]);
        return;
    }
    d -= 32768;
    if (d < 16384){ split_store(enc[d], &g_enchi[d], &g_enclo[d]); return; }
    d -= 16384;
    if (d < 131072){ split_store(cr[d], &g_crhi[d], &g_crlo[d]); return; }
    d -= 131072;
    if (d < 65536){ split_store(ac[d], &g_achi[d], &g_aclo[d]); return; }
    d -= 65536;
    { int e = d >> 9, j = d & 511; split_store(aW[j*16 + e], &g_qWhi[d], &g_qWlo[d]); }
}

// ---------------- front-end: pack-max winner + conflict-free sparse conv1 ----------------
__global__ __launch_bounds__(256) void frontend_kernel(const int* __restrict__ obs,
                                                       const float* __restrict__ b1)
{
    const int b = blockIdx.x, tid = threadIdx.x;
    __shared__ int   s_cellA[200];
    __shared__ float s_cval[200];
    __shared__ int   s_pack[8192];           // 32 KB; reused as part[4][16][64] (16 KB)
    float* part = (float*)s_pack;

    // phase 0: load my token, init referenced cells
    int my_cell = 0, my_pack = 0, my_coord = 255, my_atr = 40;
    if (tid < 200){
        const int* t = &obs[b*600 + tid*3];
        my_coord = t[0]; my_atr = t[1];
        int val = t[2];
        bool valid = (my_coord != 255) && (my_atr < 32);
        int x = (my_coord >> 4) & 15, y = my_coord & 15;
        my_cell = valid ? (my_atr*256 + x*16 + y) : 0;   // invalid claims cell 0 (ref semantics)
        my_pack = tid*256 + (valid ? val : 0);           // pack: last index wins, carries value
        s_pack[my_cell] = -1;                            // init only referenced cells
    }
    __syncthreads();
    if (tid < 200) atomicMax(&s_pack[my_cell], my_pack);
    __syncthreads();
    if (tid < 200){
        bool kept = (s_pack[my_cell] == my_pack);
        bool valid = (my_coord != 255) && (my_atr < 32);
        int x = (my_coord >> 4) & 15, y = my_coord & 15;
        s_cellA[tid] = my_cell;
        // x>=14 / y>=14 never read by 5x5/s3 VALID conv
        s_cval[tid] = (kept && valid && x < 14 && y < 14) ? (float)(my_pack & 255) : 0.f;
    }
    __syncthreads();
    for (int k = tid; k < 4096; k += 256) part[k] = 0.f;  // overlay: zero conv1 partials
    __syncthreads();

    // sparse conv1 scatter: part[g][pos][oc], lane = oc -> conflict-free LDS atomics
    {
        const int oc = tid & 63, g = tid >> 6;
        float* pg = &part[g*1024 + oc];
        #pragma unroll 2
        for (int k = g; k < 200; k += 4){
            float v = s_cval[k];
            if (v != 0.f){                                // wave-uniform predicate
                int c = s_cellA[k];
                int l = c >> 8, x = (c >> 4) & 15, y = c & 15;
                int x3 = x/3, rx = x - 3*x3;
                int y3 = y/3, ry = y - 3*y3;
                const float* wl = &g_w1t[l*1600 + oc];
                bool ax = (x3 <= 3), bx = (x3 >= 1) && (rx <= 1);
                bool ay = (y3 <= 3), by = (y3 >= 1) && (ry <= 1);
                if (ax && ay) atomicAdd(&pg[(x3*4 + y3)*64],       v*wl[(rx*5+ry)*64]);
                if (ax && by) atomicAdd(&pg[(x3*4 + y3-1)*64],     v*wl[(rx*5+ry+3)*64]);
                if (bx && ay) atomicAdd(&pg[((x3-1)*4 + y3)*64],   v*wl[((rx+3)*5+ry)*64]);
                if (bx && by) atomicAdd(&pg[((x3-1)*4 + y3-1)*64], v*wl[((rx+3)*5+ry+3)*64]);
            }
        }
    }
    __syncthreads();

    // reduce groups + bias + relu, split-store compact act1 [cell16][oc]
    for (int r = 0; r < 4; r++){
        int o = tid + 256*r;                 // o = cell16*64 + oc
        int oc = o & 63;
        float s = part[o] + part[1024+o] + part[2048+o] + part[3072+o] + b1[oc];
        float v = fmaxf(s, 0.f);
        unsigned short h = f2bf(v);
        g_ACT1hi[b*1024 + o] = h;
        g_ACT1lo[b*1024 + o] = f2bf(v - bf2f(h));
    }
}

// ---------------- conv2: im2col-on-load MFMA GEMM (M=32768, N=64, K=576) ----------------
__global__ __launch_bounds__(256) void conv2_kernel(const float* __restrict__ bias)
{
    const int r0 = blockIdx.x * 64;                      // 16 samples x 4 pos
    const int tid = threadIdx.x, wave = tid >> 6, lane = tid & 63;
    const int l15 = lane & 15, lhi = lane >> 4;

    __shared__ unsigned short sAhi[64][72];
    __shared__ unsigned short sAlo[64][72];

    f32x4 acc[4] = {{0,0,0,0},{0,0,0,0},{0,0,0,0},{0,0,0,0}};
    for (int kc = 0; kc < 9; kc++){                      // (kx,ky) chunk of 64 k's
        const int kx = kc / 3, ky = kc - 3*kx;
        __syncthreads();
        #pragma unroll
        for (int u = 0; u < 2; u++){
            int unit = tid + u*256;
            int row = unit >> 3, ch8 = (unit & 7) * 8;
            int px = (row >> 1) & 1, py = row & 1;       // pos = row&3
            int cell = (px + kx)*4 + (py + ky);
            int g = ((r0 >> 2) + (row >> 2))*1024 + cell*64 + ch8;
            *(short8*)&sAhi[row][ch8] = *(const short8*)&g_ACT1hi[g];
            *(short8*)&sAlo[row][ch8] = *(const short8*)&g_ACT1lo[g];
        }
        __syncthreads();
        #pragma unroll
        for (int ks = 0; ks < 2; ks++){
            const int kk = ks*32 + lhi*8;
            short8 ah = *(const short8*)&sAhi[wave*16 + l15][kk];
            short8 al = *(const short8*)&sAlo[wave*16 + l15][kk];
            #pragma unroll
            for (int nt = 0; nt < 4; nt++){
                const int n = nt*16 + l15;
                const short8 bh = *(const short8*)&g_w2hi[n*576 + kc*64 + kk];
                const short8 bl = *(const short8*)&g_w2lo[n*576 + kc*64 + kk];
                acc[nt] = __builtin_amdgcn_mfma_f32_16x16x32_bf16(ah, bh, acc[nt], 0, 0, 0);
                acc[nt] = __builtin_amdgcn_mfma_f32_16x16x32_bf16(al, bh, acc[nt], 0, 0, 0);
                acc[nt] = __builtin_amdgcn_mfma_f32_16x16x32_bf16(ah, bl, acc[nt], 0, 0, 0);
            }
        }
    }
    #pragma unroll
    for (int nt = 0; nt < 4; nt++){
        const int col = nt*16 + l15;
        const float bb = bias[col];
        #pragma unroll
        for (int j = 0; j < 4; j++){
            const int row = r0 + wave*16 + lhi*4 + j;
            float v = fmaxf(acc[nt][j] + bb, 0.f);
            unsigned short h = f2bf(v);
            g_A1hi[row*64 + col] = h;                    // == [s][pos*64+oc]
            g_A1lo[row*64 + col] = f2bf(v - bf2f(h));
        }
    }
}

// ---------------- generic 64x64 split-bf16 MFMA GEMM with relu+bias ----------
// LAYER: 1=fc1(K256,N128) 2=enc(K128,N128) 3=actor(K128,N512)
template<int LAYER>
__global__ __launch_bounds__(256) void gemm64_kernel(const float* __restrict__ bias)
{
    constexpr int K = (LAYER==1) ? 256 : 128;
    constexpr int N = (LAYER==3) ? 512 : 128;
    const unsigned short *Ahi, *Alo, *Bh, *Bl;
    unsigned short *Chi, *Clo;
    if constexpr (LAYER==1){ Ahi=g_A1hi; Alo=g_A1lo; Bh=g_fc1hi; Bl=g_fc1lo; Chi=g_A2hi; Clo=g_A2lo; }
    else if constexpr (LAYER==2){ Ahi=g_A2hi; Alo=g_A2lo; Bh=g_enchi; Bl=g_enclo; Chi=g_Hhi;  Clo=g_Hlo; }
    else                        { Ahi=g_Hhi;  Alo=g_Hlo;  Bh=g_achi;  Bl=g_aclo;  Chi=g_AFhi; Clo=g_AFlo; }

    const int r0 = blockIdx.x * 64, c0 = blockIdx.y * 64;
    const int tid = threadIdx.x, wave = tid >> 6, lane = tid & 63;
    const int l15 = lane & 15, lhi = lane >> 4;

    __shared__ unsigned short sAhi[64][72];
    __shared__ unsigned short sAlo[64][72];

    f32x4 acc[4] = {{0,0,0,0},{0,0,0,0},{0,0,0,0},{0,0,0,0}};
    for (int kb = 0; kb < K; kb += 64){
        __syncthreads();
        #pragma unroll
        for (int u = 0; u < 2; u++){
            int unit = tid + u*256;
            int row = unit >> 3, ch = (unit & 7) * 8;
            int g = (r0 + row)*K + kb + ch;
            *(short8*)&sAhi[row][ch] = *(const short8*)&Ahi[g];
            *(short8*)&sAlo[row][ch] = *(const short8*)&Alo[g];
        }
        __syncthreads();
        #pragma unroll
        for (int ks = 0; ks < 2; ks++){
            const int kk = ks*32 + lhi*8;
            short8 ah = *(const short8*)&sAhi[wave*16 + l15][kk];
            short8 al = *(const short8*)&sAlo[wave*16 + l15][kk];
            #pragma unroll
            for (int nt = 0; nt < 4; nt++){
                const int n = c0 + nt*16 + l15;
                const short8 bh = *(const short8*)&Bh[n*K + kb + kk];
                const short8 bl = *(const short8*)&Bl[n*K + kb + kk];
                acc[nt] = __builtin_amdgcn_mfma_f32_16x16x32_bf16(ah, bh, acc[nt], 0, 0, 0);
                acc[nt] = __builtin_amdgcn_mfma_f32_16x16x32_bf16(al, bh, acc[nt], 0, 0, 0);
                acc[nt] = __builtin_amdgcn_mfma_f32_16x16x32_bf16(ah, bl, acc[nt], 0, 0, 0);
            }
        }
    }
    #pragma unroll
    for (int nt = 0; nt < 4; nt++){
        const int col = c0 + nt*16 + l15;
        const float bb = bias[col];
        #pragma unroll
        for (int j = 0; j < 4; j++){
            const int row = r0 + wave*16 + lhi*4 + j;
            float v = fmaxf(acc[nt][j] + bb, 0.f);
            unsigned short h = f2bf(v);
            Chi[row*N + col] = h;
            Clo[row*N + col] = f2bf(v - bf2f(h));
        }
    }
}

// ---------------- critic: [16 rows] x 1024 cols, tanh + vw dot -> value ----------------
__global__ __launch_bounds__(256) void critic_kernel(const float* __restrict__ crb,
    const float* __restrict__ vw, const float* __restrict__ vb, float* __restrict__ outv)
{
    const int r0 = blockIdx.x * 16;
    const int tid = threadIdx.x, wave = tid >> 6, lane = tid & 63;
    const int l15 = lane & 15, lhi = lane >> 4;
    __shared__ unsigned short sAhi[16][136], sAlo[16][136];
    __shared__ float s_v[4][16];
    {
        int row = tid >> 4, ch = (tid & 15) * 8;
        int g = (r0 + row)*128 + ch;
        *(short8*)&sAhi[row][ch] = *(const short8*)&g_Hhi[g];
        *(short8*)&sAlo[row][ch] = *(const short8*)&g_Hlo[g];
    }
    __syncthreads();
    f32x4 acc[16];
    #pragma unroll
    for (int nt = 0; nt < 16; nt++) acc[nt] = f32x4{0,0,0,0};
    #pragma unroll
    for (int ks = 0; ks < 4; ks++){
        const int kk = ks*32 + lhi*8;
        short8 ah = *(const short8*)&sAhi[l15][kk];
        short8 al = *(const short8*)&sAlo[l15][kk];
        #pragma unroll
        for (int nt = 0; nt < 16; nt++){
            const int n = wave*256 + nt*16 + l15;
            const short8 bh = *(const short8*)&g_crhi[n*128 + kk];
            const short8 bl = *(const short8*)&g_crlo[n*128 + kk];
            acc[nt] = __builtin_amdgcn_mfma_f32_16x16x32_bf16(ah, bh, acc[nt], 0, 0, 0);
            acc[nt] = __builtin_amdgcn_mfma_f32_16x16x32_bf16(al, bh, acc[nt], 0, 0, 0);
            acc[nt] = __builtin_amdgcn_mfma_f32_16x16x32_bf16(ah, bl, acc[nt], 0, 0, 0);
        }
    }
    float vp[4] = {0.f, 0.f, 0.f, 0.f};
    #pragma unroll
    for (int nt = 0; nt < 16; nt++){
        const int col = wave*256 + nt*16 + l15;
        const float w = vw[col], bb = crb[col];
        #pragma unroll
        for (int j = 0; j < 4; j++) vp[j] += tanhf(acc[nt][j] + bb) * w;
    }
    #pragma unroll
    for (int m = 1; m < 16; m <<= 1){
        #pragma unroll
        for (int j = 0; j < 4; j++) vp[j] += __shfl_xor(vp[j], m, 64);
    }
    if (l15 == 0){
        #pragma unroll
        for (int j = 0; j < 4; j++) s_v[wave][lhi*4 + j] = vp[j];
    }
    __syncthreads();
    if (tid < 16)
        outv[r0 + tid] = s_v[0][tid] + s_v[1][tid] + s_v[2][tid] + s_v[3][tid] + vb[0];
}

// ---------------- query (AF @ actor_W^T, tanh) fused with logits ----------------
__global__ __launch_bounds__(256) void query_kernel(const float* __restrict__ emb,
    const float* __restrict__ abias, float* __restrict__ out)
{
    const int r0 = blockIdx.x * 64;
    const int tid = threadIdx.x, wave = tid >> 6, lane = tid & 63;
    const int l15 = lane & 15, lhi = lane >> 4;
    __shared__ unsigned short sAhi[64][72], sAlo[64][72];
    __shared__ float s_q[64][16];
    __shared__ float s_emb[1600];
    for (int k = tid; k < 1600; k += 256) s_emb[k] = emb[k];
    f32x4 acc = {0,0,0,0};
    for (int kb = 0; kb < 512; kb += 64){
        __syncthreads();
        #pragma unroll
        for (int u = 0; u < 2; u++){
            int unit = tid + u*256;
            int row = unit >> 3, ch = (unit & 7) * 8;
            int g = (r0 + row)*512 + kb + ch;
            *(short8*)&sAhi[row][ch] = *(const short8*)&g_AFhi[g];
            *(short8*)&sAlo[row][ch] = *(const short8*)&g_AFlo[g];
        }
        __syncthreads();
        #pragma unroll
        for (int ks = 0; ks < 2; ks++){
            const int kk = ks*32 + lhi*8;
            short8 ah = *(const short8*)&sAhi[wave*16 + l15][kk];
            short8 al = *(const short8*)&sAlo[wave*16 + l15][kk];
            const short8 bh = *(const short8*)&g_qWhi[l15*512 + kb + kk];
            const short8 bl = *(const short8*)&g_qWlo[l15*512 + kb + kk];
            acc = __builtin_amdgcn_mfma_f32_16x16x32_bf16(ah, bh, acc, 0, 0, 0);
            acc = __builtin_amdgcn_mfma_f32_16x16x32_bf16(al, bh, acc, 0, 0, 0);
            acc = __builtin_amdgcn_mfma_f32_16x16x32_bf16(ah, bl, acc, 0, 0, 0);
        }
    }
    #pragma unroll
    for (int j = 0; j < 4; j++)
        s_q[wave*16 + lhi*4 + j][l15] = tanhf(acc[j]);
    __syncthreads();
    for (int i = tid; i < 6400; i += 256){
        int row = i / 100, a = i - row*100;
        float s = abias[0];
        #pragma unroll
        for (int e = 0; e < 16; e++) s += s_q[row][e] * s_emb[a*16 + e];
        out[(r0 + row)*100 + a] = s;
    }
}

// ---------------- launch ----------------
extern "C" void kernel_launch(void* const* d_in, const int* in_sizes, int n_in,
                              void* d_out, int out_size, void* d_ws, size_t ws_size,
                              hipStream_t stream) {
    const int*   obs   = (const int*)  d_in[0];
    const float* maxv  = (const float*)d_in[1];
    const float* w1    = (const float*)d_in[2];
    const float* b1    = (const float*)d_in[3];
    const float* w2    = (const float*)d_in[4];
    const float* b2    = (const float*)d_in[5];
    const float* fc1w  = (const float*)d_in[6];
    const float* fc1b  = (const float*)d_in[7];
    const float* encw  = (const float*)d_in[8];
    const float* encb  = (const float*)d_in[9];
    const float* crw   = (const float*)d_in[10];
    const float* crb   = (const float*)d_in[11];
    const float* vw    = (const float*)d_in[12];
    const float* vb    = (const float*)d_in[13];
    const float* acw   = (const float*)d_in[14];
    const float* acb   = (const float*)d_in[15];
    const float* emb   = (const float*)d_in[16];
    const float* aW    = (const float*)d_in[17];
    const float* abias = (const float*)d_in[18];
    float* out = (float*)d_out;

    prep_kernel<<<1336, 256, 0, stream>>>(w1, maxv, w2, fc1w, encw, crw, acw, aW);
    frontend_kernel<<<B_, 256, 0, stream>>>(obs, b1);
    conv2_kernel<<<512, 256, 0, stream>>>(b2);
    gemm64_kernel<1><<<dim3(128, 2), 256, 0, stream>>>(fc1b);  // fc1
    gemm64_kernel<2><<<dim3(128, 2), 256, 0, stream>>>(encb);  // enc
    gemm64_kernel<3><<<dim3(128, 8), 256, 0, stream>>>(acb);   // actor
    critic_kernel<<<512, 256, 0, stream>>>(crb, vw, vb, out + B_*100);
    query_kernel<<<128, 256, 0, stream>>>(emb, abias, out);
}